// Round 1
// 141.447 us; speedup vs baseline: 1.0100x; 1.0100x over previous
//
#include <hip/hip_runtime.h>
#include <stdint.h>

#define NN 8192
#define NE 16384
#define DD 64
#define GCAP 512          // hard cap on generator count (expected ~164, Binomial(8192,~0.02))
#define SLICES 32         // j-dimension split: 32 slices x 256 j
#define NEGV -1e10f
#define TINYF 1.17549435e-38f
#define SQRT2F 1.41421356237f

// ---------------- JAX threefry2x32 (partitionable mode) ----------------
__device__ __forceinline__ uint2 tf2x32(uint32_t k0, uint32_t k1, uint32_t x0, uint32_t x1) {
  uint32_t ks2 = k0 ^ k1 ^ 0x1BD11BDAu;
  x0 += k0; x1 += k1;
#define TF_R(r) { x0 += x1; x1 = (x1 << (r)) | (x1 >> (32 - (r))); x1 ^= x0; }
  TF_R(13) TF_R(15) TF_R(26) TF_R(6)
  x0 += k1; x1 += ks2 + 1u;
  TF_R(17) TF_R(29) TF_R(16) TF_R(24)
  x0 += ks2; x1 += k0 + 2u;
  TF_R(13) TF_R(15) TF_R(26) TF_R(6)
  x0 += k0; x1 += k1 + 3u;
  TF_R(17) TF_R(29) TF_R(16) TF_R(24)
  x0 += k1; x1 += ks2 + 4u;
  TF_R(13) TF_R(15) TF_R(26) TF_R(6)
  x0 += ks2; x1 += k0 + 5u;
#undef TF_R
  return make_uint2(x0, x1);
}
__device__ __forceinline__ uint2 jax_subkey(uint32_t i) { return tf2x32(0u, 42u, 0u, i); }
__device__ __forceinline__ uint32_t rbits(uint2 k, uint32_t idx) {
  uint2 r = tf2x32(k.x, k.y, 0u, idx);
  return r.x ^ r.y;
}
__device__ __forceinline__ float u01f(uint32_t b) {
  return __uint_as_float((b >> 9) | 0x3F800000u) - 1.0f;
}
__device__ __forceinline__ float erfinv_xla(float x) {
  float w = -log1pf(-x * x);
  float p;
  if (w < 5.0f) {
    w -= 2.5f;
    p = 2.81022636e-08f;
    p = fmaf(p, w, 3.43273939e-07f);
    p = fmaf(p, w, -3.5233877e-06f);
    p = fmaf(p, w, -4.39150654e-06f);
    p = fmaf(p, w, 0.00021858087f);
    p = fmaf(p, w, -0.00125372503f);
    p = fmaf(p, w, -0.00417768164f);
    p = fmaf(p, w, 0.246640727f);
    p = fmaf(p, w, 1.50140941f);
  } else {
    w = sqrtf(w) - 3.0f;
    p = -0.000200214257f;
    p = fmaf(p, w, 0.000100950558f);
    p = fmaf(p, w, 0.00134934322f);
    p = fmaf(p, w, -0.00367342844f);
    p = fmaf(p, w, 0.00573950773f);
    p = fmaf(p, w, -0.0076224613f);
    p = fmaf(p, w, 0.00943887047f);
    p = fmaf(p, w, 1.00167406f);
    p = fmaf(p, w, 2.83297682f);
  }
  return p * x;
}
__device__ __forceinline__ float jax_normal(uint2 k, uint32_t idx) {
  float f = u01f(rbits(k, idx));
  float lo = __uint_as_float(0xBF7FFFFFu);
  float u = fmaxf(lo, f * 2.0f + lo);
  return SQRT2F * erfinv_xla(u);
}
__device__ __forceinline__ float jax_gumbel(uint2 k, uint32_t idx) {
  float f = u01f(rbits(k, idx));
  float u = fmaxf(TINYF, f + TINYF);
  return -logf(-logf(u));
}
// sortable packed argmax key: max y wins, ties -> lowest j
__device__ __forceinline__ unsigned long long packkey(float y, int j) {
  uint32_t b = __float_as_uint(y);
  b = (b & 0x80000000u) ? ~b : (b | 0x80000000u);
  return ((unsigned long long)b << 32) | (unsigned long long)(0xFFFFFFFFu - (uint32_t)j);
}

// ws scalars: 0=G 1=e_active 2=allowed 3=kept_total 4=n_gens 5=done-counter

// ---- K1: per-node hn/probs/bernoulli (blocks 0..2047) + aedges cumsum (block 2048) ----
__global__ void sg_gens_scan(const float* __restrict__ nodes, const float* __restrict__ Wp,
                             const float* __restrict__ bp, const float* __restrict__ anodes,
                             const float* __restrict__ aedges, int* __restrict__ gens0,
                             float* __restrict__ hn, int* __restrict__ c, int* __restrict__ sc) {
  if (blockIdx.x >= 2048) {
    // inclusive int cumsum of (aedges != 0) — runs concurrently with gens blocks
    __shared__ int ts[256];
    int t = threadIdx.x;
    int base = t * 64;
    uint64_t bits = 0;
    int s = 0;
    const float4* a4 = (const float4*)(aedges + base);
    for (int k4 = 0; k4 < 16; k4++) {
      float4 v = a4[k4];
      if (v.x != 0.0f) { bits |= 1ull << (4 * k4 + 0); s++; }
      if (v.y != 0.0f) { bits |= 1ull << (4 * k4 + 1); s++; }
      if (v.z != 0.0f) { bits |= 1ull << (4 * k4 + 2); s++; }
      if (v.w != 0.0f) { bits |= 1ull << (4 * k4 + 3); s++; }
    }
    ts[t] = s;
    __syncthreads();
    for (int off = 1; off < 256; off <<= 1) {
      int add = (t >= off) ? ts[t - off] : 0;
      __syncthreads();
      ts[t] += add;
      __syncthreads();
    }
    int run = ts[t] - s;
    for (int k = 0; k < 64; k++) {
      run += (int)((bits >> k) & 1ull);
      c[base + k] = run;
    }
    if (t == 255) { sc[1] = ts[255]; sc[2] = NE - ts[255] - 1; }
    return;
  }
  int lane = threadIdx.x & 63;
  int i = blockIdx.x * 4 + (threadIdx.x >> 6);
  float v = nodes[i * DD + lane];
  float ss = v * v;
  float dp = v * Wp[lane];
  for (int off = 32; off > 0; off >>= 1) {
    ss += __shfl_xor(ss, off, 64);
    dp += __shfl_xor(dp, off, 64);
  }
  if (lane == 0) {
    hn[i] = ss;
    float x = dp + bp[0];
    float p = 1.0f / (1.0f + expf(-x));
    uint2 kp = jax_subkey(0u);
    float u = u01f(rbits(kp, (uint32_t)i));
    gens0[i] = (u < p * anodes[i]) ? 1 : 0;
  }
}

// ---- K2: compact generator node ids + init keptf/asel/done-counter (single block) ----
__global__ void sg_compact(const int* __restrict__ gens0, int* __restrict__ gidx,
                           int* __restrict__ sc, int* __restrict__ keptf,
                           unsigned long long* __restrict__ asel) {
  __shared__ int ts[256];
  int t = threadIdx.x;
  int b2 = t * 32;
  uint32_t gb = 0;
  int s2 = 0;
  const int4* g4 = (const int4*)(gens0 + b2);
  for (int k4 = 0; k4 < 8; k4++) {
    int4 v = g4[k4];
    if (v.x) { gb |= 1u << (4 * k4 + 0); s2++; }
    if (v.y) { gb |= 1u << (4 * k4 + 1); s2++; }
    if (v.z) { gb |= 1u << (4 * k4 + 2); s2++; }
    if (v.w) { gb |= 1u << (4 * k4 + 3); s2++; }
  }
  ts[t] = s2;
  // init while the scan barrier settles
  keptf[2 * t] = 1; keptf[2 * t + 1] = 1;
  asel[2 * t] = 0ull; asel[2 * t + 1] = 0ull;
  if (t == 0) sc[5] = 0;  // done-counter for K4's last-block rank (reset every launch)
  __syncthreads();
  for (int off = 1; off < 256; off <<= 1) {
    int add = (t >= off) ? ts[t - off] : 0;
    __syncthreads();
    ts[t] += add;
    __syncthreads();
  }
  int r = ts[t] - s2;
  for (int k = 0; k < 32; k++)
    if ((gb >> k) & 1u) gidx[r++] = b2 + k;
  if (t == 255) sc[0] = ts[255];
}

// ---- K3: fused query + partial argmax of score+gumbel; global argmax via atomicMax ----
__global__ __launch_bounds__(256) void sg_part(
    const float* __restrict__ nodes, const float* __restrict__ anodes,
    const float* __restrict__ hn, const int* __restrict__ gidx,
    const int* __restrict__ sc, const float* __restrict__ Wq,
    const float* __restrict__ bq, unsigned long long* __restrict__ asel) {
  __shared__ float sq[4][DD];
  __shared__ float sn[4][DD];
  __shared__ float sqn[4];
  __shared__ int si[4];
  __shared__ float wy[4][4];
  __shared__ int wj[4][4];
  int G = min(sc[0], GCAP);
  int nGq = (G + 3) >> 2;
  int total = nGq * SLICES;
  int t = threadIdx.x;
  int wid = t >> 6, lane = t & 63;
  uint2 ks = jax_subkey(2u);
  for (int item = blockIdx.x; item < total; item += gridDim.x) {
    int gq = item >> 5, s = item & 31;
    int g0 = gq * 4;
    if (t < 4) {
      int g = g0 + t;
      si[t] = (g < G) ? gidx[g] : -1;
    }
    __syncthreads();
    // stage the 4 generator node rows
    int iu_w = si[wid];
    sn[wid][lane] = (iu_w >= 0) ? nodes[(size_t)iu_w * DD + lane] : 0.0f;
    __syncthreads();
    // compute query q[u=wid][dim=lane] = nodes[i] @ Wq + bq, and its squared norm
    float q = bq[lane];
#pragma unroll
    for (int k = 0; k < DD; k++) q = fmaf(sn[wid][k], Wq[k * DD + lane], q);
    sq[wid][lane] = q;
    float ssq = q * q;
    for (int off = 32; off > 0; off >>= 1) ssq += __shfl_xor(ssq, off, 64);
    if (lane == 0) sqn[wid] = ssq;
    __syncthreads();
    int j = s * 256 + t;
    float4 nv[16];
    const float4* np4 = (const float4*)(nodes + (size_t)j * DD);
    for (int k4 = 0; k4 < 16; k4++) nv[k4] = np4[k4];
    float hnj = hn[j];
    float act = anodes[j];
    float yy[4];
    for (int u = 0; u < 4; u++) {
      int iu = si[u];
      if (iu < 0) { yy[u] = -INFINITY; continue; }
      float num = 0.0f;
      for (int k4 = 0; k4 < 16; k4++) {
        const float4 qv = *(const float4*)&sq[u][4 * k4];
        num += nv[k4].x * qv.x + nv[k4].y * qv.y + nv[k4].z * qv.z + nv[k4].w * qv.w;
      }
      float denom = sqrtf(sqn[u] * hnj) + 1e-8f;
      float sco = num / denom;
      sco = fminf(fmaxf(sco, -10000.0f), 10000.0f);
      if (!(act > 0.0f)) sco = NEGV;
      if (j == iu) sco = NEGV;
      yy[u] = sco + jax_gumbel(ks, (uint32_t)iu * (uint32_t)NN + (uint32_t)j);
    }
    // wave-level argmax (lowest-j tiebreak) per u
    for (int u = 0; u < 4; u++) {
      float y = yy[u];
      int bj = j;
      for (int off = 32; off > 0; off >>= 1) {
        float oy = __shfl_xor(y, off, 64);
        int oj = __shfl_xor(bj, off, 64);
        if (oy > y || (oy == y && oj < bj)) { y = oy; bj = oj; }
      }
      if (lane == 0) { wy[u][wid] = y; wj[u][wid] = bj; }
    }
    __syncthreads();
    if (t < 4 && g0 + t < G) {
      int u = t;
      float y = wy[u][0];
      int bj = wj[u][0];
      for (int w = 1; w < 4; w++) {
        if (wy[u][w] > y || (wy[u][w] == y && wj[u][w] < bj)) { y = wy[u][w]; bj = wj[u][w]; }
      }
      atomicMax(&asel[g0 + u], packkey(y, bj));
    }
    __syncthreads();
  }
}

// ---- K4: duplicate-edge rejection (edge-parallel) + last-block rank/clip ----
__global__ void sg_exist_rank(const int* __restrict__ senders, const int* __restrict__ receivers,
                              const int* __restrict__ gidx,
                              const unsigned long long* __restrict__ asel,
                              int* __restrict__ sc, int* __restrict__ keptf,
                              int* __restrict__ fid, int* __restrict__ fsel) {
  __shared__ int lg[GCAP], ls[GCAP];
  __shared__ int ts[256];
  __shared__ int lastflag;
  int G = min(sc[0], GCAP);
  int t = threadIdx.x;
  for (int g = t; g < G; g += 256) {
    lg[g] = gidx[g];
    ls[g] = (int)(0xFFFFFFFFu - (uint32_t)(asel[g] & 0xFFFFFFFFull));
  }
  __syncthreads();
  int e = blockIdx.x * 256 + t;
  int se = senders[e], re = receivers[e];
  for (int g = 0; g < G; g++)
    if (se == lg[g] && re == ls[g]) atomicAnd(&keptf[g], 0);  // device-scope RMW
  __threadfence();
  __syncthreads();
  if (t == 0) lastflag = (atomicAdd(&sc[5], 1) == (int)gridDim.x - 1);
  __syncthreads();
  if (!lastflag) return;
  // last block: rank kept generators, clip n_gens
  __threadfence();
  int g0i = 2 * t, g1i = 2 * t + 1;
  int kv0 = (g0i < G) ? atomicAdd(&keptf[g0i], 0) : 0;  // coherent read
  int kv1 = (g1i < G) ? atomicAdd(&keptf[g1i], 0) : 0;
  int s = kv0 + kv1;
  ts[t] = s;
  __syncthreads();
  for (int off = 1; off < 256; off <<= 1) {
    int add = (t >= off) ? ts[t - off] : 0;
    __syncthreads();
    ts[t] += add;
    __syncthreads();
  }
  int r = ts[t] - s;
  if (kv0) { fid[r] = lg[g0i]; fsel[r] = ls[g0i]; r++; }
  if (kv1) { fid[r] = lg[g1i]; fsel[r] = ls[g1i]; }
  if (t == 255) {
    int kt = ts[255];
    int allowed = sc[2];
    int ng = kt > 0 ? kt : 0;
    if (ng > allowed) ng = allowed;
    sc[3] = kt; sc[4] = ng;
  }
}

// ---- K5: fused new_edges + naedges/nsend/nrec outputs ----
__global__ void sg_out(const float* __restrict__ edges, const float* __restrict__ aedges,
                       const int* __restrict__ senders, const int* __restrict__ receivers,
                       const int* __restrict__ c, const int* __restrict__ sc,
                       const int* __restrict__ fid, const int* __restrict__ fsel,
                       float* __restrict__ out_edges, float* __restrict__ out_send,
                       float* __restrict__ out_rec, float* __restrict__ out_na) {
  int t = threadIdx.x;
  int t4 = blockIdx.x * 256 + t;  // float4 index
  float4 v = ((const float4*)edges)[t4];
  int e = t4 >> 4;
  int n = sc[4];
  int ce = c[e];
  int pidx = e - n - 1;
  int prev = (pidx >= 0) ? c[pidx] : 0;
  int na = ((ce - prev) > 0 && e != NE - 1) ? 1 : 0;
  float mv = na ? (1.0f - aedges[e]) : 0.0f;
  if (mv != 0.0f) {
    uint2 ke = jax_subkey(1u);
    uint32_t base = (uint32_t)t4 * 4u;
    v.x += jax_normal(ke, base + 0u) * mv;
    v.y += jax_normal(ke, base + 1u) * mv;
    v.z += jax_normal(ke, base + 2u) * mv;
    v.w += jax_normal(ke, base + 3u) * mv;
  }
  ((float4*)out_edges)[t4] = v;
  if (t < 16) {
    int ee = blockIdx.x * 16 + t;
    int ce2 = c[ee];
    int p2 = ee - n - 1;
    int prev2 = (p2 >= 0) ? c[p2] : 0;
    int na2 = ((ce2 - prev2) > 0 && ee != NE - 1) ? 1 : 0;
    float a2 = aedges[ee];
    float mv2 = na2 ? (1.0f - a2) : 0.0f;
    float ns, nr;
    if (!na2) {
      ns = nr = (float)(NN - 1);
    } else if (mv2 > 0.0f) {
      int r = ee - sc[1];
      bool ok = (r >= 0 && r < sc[3]);
      ns = ok ? (float)fid[r] : 0.0f;
      nr = ok ? (float)fsel[r] : 0.0f;
    } else {
      ns = (float)senders[ee];
      nr = (float)receivers[ee];
    }
    out_send[ee] = ns;
    out_rec[ee] = nr;
    out_na[ee] = (float)na2;
  }
}

extern "C" void kernel_launch(void* const* d_in, const int* in_sizes, int n_in,
                              void* d_out, int out_size, void* d_ws, size_t ws_size,
                              hipStream_t stream) {
  const float* nodes     = (const float*)d_in[0];
  const float* edges     = (const float*)d_in[1];
  const int*   receivers = (const int*)d_in[2];
  const int*   senders   = (const int*)d_in[3];
  const float* anodes    = (const float*)d_in[4];
  const float* aedges    = (const float*)d_in[5];
  const float* Wq        = (const float*)d_in[6];
  const float* bq        = (const float*)d_in[7];
  const float* Wp        = (const float*)d_in[8];
  const float* bp        = (const float*)d_in[9];

  float* out       = (float*)d_out;
  float* out_edges = out;
  float* out_send  = out + (size_t)NE * DD;
  float* out_rec   = out_send + NE;
  float* out_na    = out_rec + NE;

  int* sc     = (int*)d_ws;         // 8 scalars
  int* gens0  = sc + 8;             // NN
  int* gidx   = gens0 + NN;         // NN (compact can write up to actual G)
  int* keptf  = gidx + NN;          // GCAP
  int* fid    = keptf + GCAP;       // GCAP
  int* fsel   = fid + GCAP;         // GCAP
  int* c      = fsel + GCAP;        // NE
  unsigned long long* asel = (unsigned long long*)(c + NE);  // GCAP, 8B-aligned offset
  float* hn   = (float*)(asel + GCAP);  // NN

  sg_gens_scan  <<<2049, 256, 0, stream>>>(nodes, Wp, bp, anodes, aedges, gens0, hn, c, sc);
  sg_compact    <<<1, 256, 0, stream>>>(gens0, gidx, sc, keptf, asel);
  sg_part       <<<4096, 256, 0, stream>>>(nodes, anodes, hn, gidx, sc, Wq, bq, asel);
  sg_exist_rank <<<NE / 256, 256, 0, stream>>>(senders, receivers, gidx, asel, sc, keptf, fid, fsel);
  sg_out        <<<NE * DD / 4 / 256, 256, 0, stream>>>(edges, aedges, senders, receivers, c, sc,
                                                        fid, fsel, out_edges, out_send, out_rec, out_na);
}